// Round 6
// baseline (534.810 us; speedup 1.0000x reference)
//
#include <hip/hip_runtime.h>
#include <hip/hip_bf16.h>
#include <stdint.h>

#define NN 100000
#define NE 600000
#define ND 128
#define ED 32
#define HID 128
#define SCANB 391  // ceil(NN/256)

using short8 = __attribute__((ext_vector_type(8))) short;
using f32x4  = __attribute__((ext_vector_type(4))) float;

// ---------- bf16 helpers (manual RNE, deterministic) ----------
__device__ __forceinline__ uint32_t f2bf(float f) {
  uint32_t u = __float_as_uint(f);
  return (u + 0x7FFFu + ((u >> 16) & 1u)) >> 16;
}
__device__ __forceinline__ short8 pack8(float4 a, float4 b) {
  short8 s;
  s[0] = (short)f2bf(a.x); s[1] = (short)f2bf(a.y);
  s[2] = (short)f2bf(a.z); s[3] = (short)f2bf(a.w);
  s[4] = (short)f2bf(b.x); s[5] = (short)f2bf(b.y);
  s[6] = (short)f2bf(b.z); s[7] = (short)f2bf(b.w);
  return s;
}

// ---------- weight pre-pack: frag-ordered bf16 ----------
__global__ __launch_bounds__(256) void k_prep(
    const float* __restrict__ W1, const float* __restrict__ W2,
    const float* __restrict__ uW1, const float* __restrict__ uW2,
    short* __restrict__ W1p, short* __restrict__ W2p,
    short* __restrict__ U1p, short* __restrict__ U2p) {
  int o = blockIdx.x * 256 + threadIdx.x;
  const float* src; short* dst; int rel;
  if (o < 36864)      { rel = o;         src = W1;  dst = W1p; }
  else if (o < 53248) { rel = o - 36864; src = W2;  dst = W2p; }
  else if (o < 86016) { rel = o - 53248; src = uW1; dst = U1p; }
  else                { rel = o - 86016; src = uW2; dst = U2p; }
  int j = rel & 7, c16 = (rel >> 3) & 15, g = (rel >> 7) & 3, nt = (rel >> 9) & 7, c = rel >> 12;
  int k = c * 32 + g * 8 + j, n = nt * 16 + c16;
  dst[rel] = (short)f2bf(src[k * 128 + n]);
}

// ---------- node features fp32 -> bf16 (gathered array shrinks 51MB -> 25.6MB) ----------
__global__ __launch_bounds__(256) void k_prep_nf(const float* __restrict__ nf,
                                                 short* __restrict__ nfb) {
  const int total = NN * ND / 8;
  for (int u = blockIdx.x * 256 + threadIdx.x; u < total; u += gridDim.x * 256) {
    const float* s = nf + (size_t)u * 8;
    float4 v0 = *(const float4*)s, v1 = *(const float4*)(s + 4);
    *(short8*)(nfb + (size_t)u * 8) = pack8(v0, v1);
  }
}

// ---------- edge MLP via MFMA, software-pipelined, 128-row tile, 3 blocks/CU ----------
__global__ __launch_bounds__(256, 3) void k_edge_mfma(
    const short* __restrict__ nfb, const float* __restrict__ ef,
    const short* __restrict__ W1p, const float* __restrict__ b1,
    const short* __restrict__ W2p, const float* __restrict__ b2,
    const float* __restrict__ aW, const int* __restrict__ ei,
    uint16_t* __restrict__ msg, float* __restrict__ logits) {
  // sMem = sH [128][132] (33792B); sA double-buffer (2x5120 shorts) aliased inside.
  __shared__ __align__(16) short sMem[128 * 132];
  __shared__ __align__(16) short sB[2][4224];  // W chunk: 32 blocks x 132 shorts (pad 4)
  __shared__ int sIdx[256];
  short* const sA0 = sMem;
  short* const sA1 = sMem + 5120;

  const int tid = threadIdx.x;
  const int wv = tid >> 6, ln = tid & 63, cr = ln & 15, gp = ln >> 4;
  const int e0 = blockIdx.x * 128;
  const int wrow = wv * 32;
  const int r0 = tid >> 2, r1 = 64 + r0, seg = tid & 3;

  if (tid < 128) {
    int e = e0 + tid; if (e >= NE) e = NE - 1;
    sIdx[tid] = ei[e];
    sIdx[128 + tid] = ei[NE + e];
  }
  __syncthreads();

  short8 pa0, pa1, pw0, pw1;
  float4 pe[4];

  auto loadA = [&](int c) {
    if (c < 8) {
      const int base = (c & 3) * 32 + seg * 8;
      const int off = (c < 4) ? 0 : 128;
      pa0 = *(const short8*)(nfb + (size_t)sIdx[off + r0] * ND + base);
      pa1 = *(const short8*)(nfb + (size_t)sIdx[off + r1] * ND + base);
    } else {
      int ea = e0 + r0; if (ea >= NE) ea = NE - 1;
      int eb = e0 + r1; if (eb >= NE) eb = NE - 1;
      const float* f0 = ef + (size_t)ea * ED + seg * 8;
      const float* f1 = ef + (size_t)eb * ED + seg * 8;
      pe[0] = *(const float4*)f0; pe[1] = *(const float4*)(f0 + 4);
      pe[2] = *(const float4*)f1; pe[3] = *(const float4*)(f1 + 4);
    }
  };
  auto storeA = [&](short* buf, int c) {
    if (c < 8) {
      *(short8*)&buf[r0 * 40 + seg * 8] = pa0;
      *(short8*)&buf[r1 * 40 + seg * 8] = pa1;
    } else {
      *(short8*)&buf[r0 * 40 + seg * 8] = pack8(pe[0], pe[1]);
      *(short8*)&buf[r1 * 40 + seg * 8] = pack8(pe[2], pe[3]);
    }
  };
  auto loadW = [&](const short* Wp, int c) {
    const short8* src = (const short8*)(Wp + c * 4096);
    pw0 = src[tid]; pw1 = src[tid + 256];
  };
  auto storeW = [&](short* buf) {
    int u0 = tid, u1 = tid + 256;
    *(short8*)&buf[(u0 >> 4) * 132 + (u0 & 15) * 8] = pw0;
    *(short8*)&buf[(u1 >> 4) * 132 + (u1 & 15) * 8] = pw1;
  };

  // prologue: stage chunk 0
  loadA(0); loadW(W1p, 0);
  storeA(sA0, 0); storeW(sB[0]);

  float bia[8], aWr[8], bia2[8];
#pragma unroll
  for (int nt = 0; nt < 8; ++nt) {
    bia[nt] = b1[nt * 16 + cr];
    bia2[nt] = b2[nt * 16 + cr];
    aWr[nt] = aW[nt * 16 + cr];
  }
  f32x4 acc[2][8];
#pragma unroll
  for (int mt = 0; mt < 2; ++mt)
#pragma unroll
    for (int nt = 0; nt < 8; ++nt)
      acc[mt][nt] = (f32x4){bia[nt], bia[nt], bia[nt], bia[nt]};

  // ---- layer 1: 9 chunks, one barrier per chunk, prefetch overlaps MFMA ----
  for (int c = 0; c < 9; ++c) {
    if (c < 8) { loadA(c + 1); loadW(W1p, c + 1); }
    __syncthreads();
    const short* bufA = (c & 1) ? sA1 : sA0;
    const short* bufB = sB[c & 1];
    short8 af0 = *(const short8*)&bufA[(wrow + cr) * 40 + gp * 8];
    short8 af1 = *(const short8*)&bufA[(wrow + 16 + cr) * 40 + gp * 8];
#pragma unroll
    for (int nt = 0; nt < 8; ++nt) {
      short8 bfr = *(const short8*)&bufB[(nt * 4 + gp) * 132 + cr * 8];
      acc[0][nt] = __builtin_amdgcn_mfma_f32_16x16x32_bf16(af0, bfr, acc[0][nt], 0, 0, 0);
      acc[1][nt] = __builtin_amdgcn_mfma_f32_16x16x32_bf16(af1, bfr, acc[1][nt], 0, 0, 0);
    }
    if (c < 8) { storeA((c & 1) ? sA0 : sA1, c + 1); storeW(sB[(c + 1) & 1]); }
  }
  __syncthreads();

  // relu -> sH (bf16)
#pragma unroll
  for (int mt = 0; mt < 2; ++mt)
#pragma unroll
    for (int nt = 0; nt < 8; ++nt)
#pragma unroll
      for (int rr = 0; rr < 4; ++rr)
        sMem[(wrow + mt * 16 + gp * 4 + rr) * 132 + nt * 16 + cr] =
            (short)f2bf(fmaxf(acc[mt][nt][rr], 0.f));
  loadW(W2p, 0); storeW(sB[0]);

  // ---- layer 2: 4 chunks ----
  f32x4 acc2[2][8];
#pragma unroll
  for (int mt = 0; mt < 2; ++mt)
#pragma unroll
    for (int nt = 0; nt < 8; ++nt)
      acc2[mt][nt] = (f32x4){bia2[nt], bia2[nt], bia2[nt], bia2[nt]};
  for (int c2 = 0; c2 < 4; ++c2) {
    if (c2 < 3) loadW(W2p, c2 + 1);
    __syncthreads();
    const short* bufB = sB[c2 & 1];
    short8 af0 = *(const short8*)&sMem[(wrow + cr) * 132 + c2 * 32 + gp * 8];
    short8 af1 = *(const short8*)&sMem[(wrow + 16 + cr) * 132 + c2 * 32 + gp * 8];
#pragma unroll
    for (int nt = 0; nt < 8; ++nt) {
      short8 bfr = *(const short8*)&bufB[(nt * 4 + gp) * 132 + cr * 8];
      acc2[0][nt] = __builtin_amdgcn_mfma_f32_16x16x32_bf16(af0, bfr, acc2[0][nt], 0, 0, 0);
      acc2[1][nt] = __builtin_amdgcn_mfma_f32_16x16x32_bf16(af1, bfr, acc2[1][nt], 0, 0, 0);
    }
    if (c2 < 3) storeW(sB[(c2 + 1) & 1]);
  }

  // attention logits (register-only; reduce over the 16 col-lanes)
#pragma unroll
  for (int mt = 0; mt < 2; ++mt)
#pragma unroll
    for (int rr = 0; rr < 4; ++rr) {
      float p = 0.f;
#pragma unroll
      for (int nt = 0; nt < 8; ++nt) p += acc2[mt][nt][rr] * aWr[nt];
      p += __shfl_xor(p, 1, 64);
      p += __shfl_xor(p, 2, 64);
      p += __shfl_xor(p, 4, 64);
      p += __shfl_xor(p, 8, 64);
      int e = e0 + wrow + mt * 16 + gp * 4 + rr;
      if (cr == 0 && e < NE) logits[e] = p;
    }

  __syncthreads();  // all sH reads done before overwriting with messages
#pragma unroll
  for (int mt = 0; mt < 2; ++mt)
#pragma unroll
    for (int nt = 0; nt < 8; ++nt)
#pragma unroll
      for (int rr = 0; rr < 4; ++rr)
        sMem[(wrow + mt * 16 + gp * 4 + rr) * 132 + nt * 16 + cr] =
            (short)f2bf(acc2[mt][nt][rr]);
  __syncthreads();
#pragma unroll
  for (int it = 0; it < 8; ++it) {
    int row = it * 16 + (tid >> 4), o8 = (tid & 15) * 8;
    int e = e0 + row;
    if (e < NE)
      *(short8*)(msg + (size_t)e * HID + o8) = *(const short8*)&sMem[row * 132 + o8];
  }
}

// ---------- node update MLP via MFMA (+ residual) — unchanged from R5 ----------
__global__ __launch_bounds__(256, 2) void k_node_mfma(
    const float* __restrict__ nf, const float* __restrict__ agg,
    const short* __restrict__ U1p, const float* __restrict__ b1,
    const short* __restrict__ U2p, const float* __restrict__ b2,
    float* __restrict__ out) {
  __shared__ __align__(16) short sA[192 * 40];
  __shared__ __align__(16) short sB[4096];
  __shared__ __align__(16) short sH[192 * 136];

  const int tid = threadIdx.x;
  const int wv = tid >> 6, ln = tid & 63, cr = ln & 15, gp = ln >> 4;
  const int n0 = blockIdx.x * 192;
  const int wrow = wv * 48;

  float bia[8], bia2[8];
#pragma unroll
  for (int nt = 0; nt < 8; ++nt) {
    bia[nt] = b1[nt * 16 + cr];
    bia2[nt] = b2[nt * 16 + cr];
  }
  f32x4 acc[3][8];
#pragma unroll
  for (int mt = 0; mt < 3; ++mt)
#pragma unroll
    for (int nt = 0; nt < 8; ++nt)
      acc[mt][nt] = (f32x4){bia[nt], bia[nt], bia[nt], bia[nt]};

  for (int c = 0; c < 8; ++c) {
#pragma unroll
    for (int it = 0; it < 3; ++it) {
      int row = it * 64 + (tid >> 2), k8 = (tid & 3) * 8;
      int n = n0 + row; if (n >= NN) n = NN - 1;
      const float* src = (c < 4) ? nf + (size_t)n * ND + c * 32 + k8
                                 : agg + (size_t)n * ND + (c - 4) * 32 + k8;
      float4 v0 = *(const float4*)src, v1 = *(const float4*)(src + 4);
      *(short8*)&sA[row * 40 + k8] = pack8(v0, v1);
    }
    {
      const short8* wsrc = (const short8*)(U1p + c * 4096);
      short8 t0 = wsrc[tid], t1 = wsrc[tid + 256];
      ((short8*)sB)[tid] = t0; ((short8*)sB)[tid + 256] = t1;
    }
    __syncthreads();
    short8 af[3];
#pragma unroll
    for (int mt = 0; mt < 3; ++mt)
      af[mt] = *(const short8*)&sA[(wrow + mt * 16 + cr) * 40 + gp * 8];
#pragma unroll
    for (int nt = 0; nt < 8; ++nt) {
      short8 bfr = *(const short8*)&sB[(nt * 4 + gp) * 128 + cr * 8];
#pragma unroll
      for (int mt = 0; mt < 3; ++mt)
        acc[mt][nt] = __builtin_amdgcn_mfma_f32_16x16x32_bf16(af[mt], bfr, acc[mt][nt], 0, 0, 0);
    }
    __syncthreads();
  }

#pragma unroll
  for (int mt = 0; mt < 3; ++mt)
#pragma unroll
    for (int nt = 0; nt < 8; ++nt)
#pragma unroll
      for (int rr = 0; rr < 4; ++rr)
        sH[(wrow + mt * 16 + gp * 4 + rr) * 136 + nt * 16 + cr] =
            (short)f2bf(fmaxf(acc[mt][nt][rr], 0.f));
  __syncthreads();

  f32x4 acc2[3][8];
#pragma unroll
  for (int mt = 0; mt < 3; ++mt)
#pragma unroll
    for (int nt = 0; nt < 8; ++nt)
      acc2[mt][nt] = (f32x4){bia2[nt], bia2[nt], bia2[nt], bia2[nt]};
  for (int c2 = 0; c2 < 4; ++c2) {
    {
      const short8* wsrc = (const short8*)(U2p + c2 * 4096);
      short8 t0 = wsrc[tid], t1 = wsrc[tid + 256];
      ((short8*)sB)[tid] = t0; ((short8*)sB)[tid + 256] = t1;
    }
    __syncthreads();
    short8 af[3];
#pragma unroll
    for (int mt = 0; mt < 3; ++mt)
      af[mt] = *(const short8*)&sH[(wrow + mt * 16 + cr) * 136 + c2 * 32 + gp * 8];
#pragma unroll
    for (int nt = 0; nt < 8; ++nt) {
      short8 bfr = *(const short8*)&sB[(nt * 4 + gp) * 128 + cr * 8];
#pragma unroll
      for (int mt = 0; mt < 3; ++mt)
        acc2[mt][nt] = __builtin_amdgcn_mfma_f32_16x16x32_bf16(af[mt], bfr, acc2[mt][nt], 0, 0, 0);
    }
    __syncthreads();
  }

#pragma unroll
  for (int mt = 0; mt < 3; ++mt)
#pragma unroll
    for (int rr = 0; rr < 4; ++rr) {
      int n = n0 + wrow + mt * 16 + gp * 4 + rr;
      if (n < NN) {
#pragma unroll
        for (int nt = 0; nt < 8; ++nt) {
          int col = nt * 16 + cr;
          out[(size_t)n * ND + col] = acc2[mt][nt][rr] + nf[(size_t)n * ND + col];
        }
      }
    }
}

// ---------- softmax reductions ----------
__device__ __forceinline__ float block_reduce_max(float m) {
#pragma unroll
  for (int s = 1; s < 64; s <<= 1) m = fmaxf(m, __shfl_xor(m, s, 64));
  __shared__ float sm[4];
  if ((threadIdx.x & 63) == 0) sm[threadIdx.x >> 6] = m;
  __syncthreads();
  return fmaxf(fmaxf(sm[0], sm[1]), fmaxf(sm[2], sm[3]));
}
__device__ __forceinline__ float block_reduce_sum(float v) {
#pragma unroll
  for (int s = 1; s < 64; s <<= 1) v += __shfl_xor(v, s, 64);
  __shared__ float sv[4];
  if ((threadIdx.x & 63) == 0) sv[threadIdx.x >> 6] = v;
  __syncthreads();
  return sv[0] + sv[1] + sv[2] + sv[3];
}

__global__ __launch_bounds__(256) void k_redmax_p(const float* __restrict__ logits,
                                                 float* __restrict__ pmax) {
  float m = -3.402823466e38f;
  for (int i = blockIdx.x * 256 + threadIdx.x; i < NE; i += 1024 * 256)
    m = fmaxf(m, logits[i]);
  m = block_reduce_max(m);
  if (threadIdx.x == 0) pmax[blockIdx.x] = m;
}
__global__ __launch_bounds__(256) void k_redmax_f(const float* __restrict__ p,
                                                 float* __restrict__ red) {
  float m = fmaxf(fmaxf(p[threadIdx.x], p[threadIdx.x + 256]),
                  fmaxf(p[threadIdx.x + 512], p[threadIdx.x + 768]));
  m = block_reduce_max(m);
  if (threadIdx.x == 0) red[0] = m;
}
__global__ __launch_bounds__(256) void k_redsum_p(const float* __restrict__ logits,
                                                 const float* __restrict__ red,
                                                 float* __restrict__ psum) {
  float gm = red[0], s = 0.f;
  for (int i = blockIdx.x * 256 + threadIdx.x; i < NE; i += 1024 * 256)
    s += expf(logits[i] - gm);
  s = block_reduce_sum(s);
  if (threadIdx.x == 0) psum[blockIdx.x] = s;
}
__global__ __launch_bounds__(256) void k_redsum_f(const float* __restrict__ p,
                                                 float* __restrict__ red) {
  float s = p[threadIdx.x] + p[threadIdx.x + 256] + p[threadIdx.x + 512] +
            p[threadIdx.x + 768];
  s = block_reduce_sum(s);
  if (threadIdx.x == 0) red[1] = 1.0f / s;
}

// ---------- CSR build ----------
__global__ __launch_bounds__(256) void k_zero_cnt(int* __restrict__ cnt) {
  int i = blockIdx.x * 256 + threadIdx.x;
  if (i < NN) cnt[i] = 0;
}
__global__ __launch_bounds__(256) void k_hist(const int* __restrict__ ei,
                                              int* __restrict__ cnt) {
  int e = blockIdx.x * 256 + threadIdx.x;
  if (e < NE) atomicAdd(&cnt[ei[NE + e]], 1);
}
__global__ __launch_bounds__(256) void k_scan_bsum(const int* __restrict__ cnt,
                                                   int* __restrict__ bsum) {
  int i = blockIdx.x * 256 + threadIdx.x;
  int v = (i < NN) ? cnt[i] : 0;
#pragma unroll
  for (int s = 1; s < 64; s <<= 1) v += __shfl_xor(v, s, 64);
  __shared__ int sv[4];
  if ((threadIdx.x & 63) == 0) sv[threadIdx.x >> 6] = v;
  __syncthreads();
  if (threadIdx.x == 0) bsum[blockIdx.x] = sv[0] + sv[1] + sv[2] + sv[3];
}
__global__ __launch_bounds__(512) void k_scan_boff(const int* __restrict__ bsum,
                                                   int* __restrict__ boff,
                                                   int* __restrict__ rowptr) {
  __shared__ int s[512];
  int t = threadIdx.x;
  int v = (t < SCANB) ? bsum[t] : 0;
  s[t] = v;
  __syncthreads();
  for (int off = 1; off < 512; off <<= 1) {
    int u = (t >= off) ? s[t - off] : 0;
    __syncthreads();
    s[t] += u;
    __syncthreads();
  }
  if (t < SCANB) boff[t] = s[t] - v;  // exclusive
  if (t == 0) rowptr[NN] = NE;
}
__global__ __launch_bounds__(256) void k_scan_final(int* __restrict__ cnt,
                                                    const int* __restrict__ boff,
                                                    int* __restrict__ rowptr) {
  __shared__ int s[256];
  int b = blockIdx.x, t = threadIdx.x, i = b * 256 + t;
  int v = (i < NN) ? cnt[i] : 0;
  s[t] = v;
  __syncthreads();
  for (int off = 1; off < 256; off <<= 1) {
    int u = (t >= off) ? s[t - off] : 0;
    __syncthreads();
    s[t] += u;
    __syncthreads();
  }
  int excl = s[t] - v + boff[b];
  if (i < NN) { rowptr[i] = excl; cnt[i] = excl; }  // cnt becomes the fill cursor
}
__global__ __launch_bounds__(256) void k_fill(const int* __restrict__ ei,
                                              int* __restrict__ cursor,
                                              int* __restrict__ eid) {
  int e = blockIdx.x * 256 + threadIdx.x;
  if (e >= NE) return;
  int c = ei[NE + e];
  int pos = atomicAdd(&cursor[c], 1);
  eid[pos] = e;
}

// ---------- CSR gather-aggregate (weights fused): one wave per node ----------
__global__ __launch_bounds__(256) void k_agg(
    const uint16_t* __restrict__ msg, const float* __restrict__ logits,
    const int* __restrict__ rowptr, const int* __restrict__ eid,
    const float* __restrict__ red, float* __restrict__ out) {
  int n = blockIdx.x * 4 + (threadIdx.x >> 6);
  int lane = threadIdx.x & 63;
  if (n >= NN) return;
  float gm = red[0], inv = red[1];
  int i0 = rowptr[n], i1 = rowptr[n + 1];
  float a0 = 0.f, a1 = 0.f;
  for (int i = i0; i < i1; ++i) {
    int e = eid[i];
    float wt = expf(logits[e] - gm) * inv;
    uint32_t pk = *(const uint32_t*)(msg + (size_t)e * HID + lane * 2);
    a0 += wt * __uint_as_float(pk << 16);
    a1 += wt * __uint_as_float(pk & 0xFFFF0000u);
  }
  *(float2*)(out + (size_t)n * ND + lane * 2) = make_float2(a0, a1);
}

extern "C" void kernel_launch(void* const* d_in, const int* in_sizes, int n_in,
                              void* d_out, int out_size, void* d_ws, size_t ws_size,
                              hipStream_t stream) {
  const float* nf  = (const float*)d_in[0];
  const float* ef  = (const float*)d_in[1];
  const float* mW1 = (const float*)d_in[2];
  const float* mb1 = (const float*)d_in[3];
  const float* mW2 = (const float*)d_in[4];
  const float* mb2 = (const float*)d_in[5];
  const float* aW  = (const float*)d_in[6];
  // d_in[7] = a_b — unused (softmax is shift-invariant)
  const float* uW1 = (const float*)d_in[8];
  const float* ub1 = (const float*)d_in[9];
  const float* uW2 = (const float*)d_in[10];
  const float* ub2 = (const float*)d_in[11];
  const int*   ei  = (const int*)d_in[12];
  float* out = (float*)d_out;

  // ws layout (bytes):
  //   0          msg bf16 [NE*128]            153,600,000
  //   153600000  logits f32 [NE]                2,400,000
  //   156000000  pmax[1024] psum[1024] red          8,256
  //   156008256  W1p/W2p/U1p/U2p packed bf16      204,800
  //   156213056  rowptr/cnt/eid/bsum/boff       3,204,100
  //   159420416  nfb bf16 [NN*128]             25,600,000   -> total ~185MB
  char* ws = (char*)d_ws;
  uint16_t* msg = (uint16_t*)ws;
  float* logits = (float*)(ws + 153600000);
  float* pmax = (float*)(ws + 156000000);
  float* psum = pmax + 1024;
  float* red  = psum + 1024;
  short* W1p = (short*)(ws + 156008256);
  short* W2p = W1p + 36864;
  short* U1p = W2p + 16384;
  short* U2p = U1p + 32768;
  int* rowptr = (int*)(ws + 156213056);
  int* cnt    = rowptr + (NN + 1);
  int* eid    = cnt + NN;
  int* bsum   = eid + NE;
  int* boff   = bsum + 512;
  short* nfb  = (short*)(ws + 159420416);

  k_prep<<<400, 256, 0, stream>>>(mW1, mW2, uW1, uW2, W1p, W2p, U1p, U2p);
  k_prep_nf<<<2048, 256, 0, stream>>>(nf, nfb);
  k_zero_cnt<<<SCANB, 256, 0, stream>>>(cnt);
  k_hist<<<(NE + 255) / 256, 256, 0, stream>>>(ei, cnt);
  k_scan_bsum<<<SCANB, 256, 0, stream>>>(cnt, bsum);
  k_scan_boff<<<1, 512, 0, stream>>>(bsum, boff, rowptr);
  k_scan_final<<<SCANB, 256, 0, stream>>>(cnt, boff, rowptr);
  k_fill<<<(NE + 255) / 256, 256, 0, stream>>>(ei, cnt, eid);
  k_edge_mfma<<<(NE + 127) / 128, 256, 0, stream>>>(nfb, ef, W1p, mb1, W2p, mb2, aW, ei, msg, logits);
  k_redmax_p<<<1024, 256, 0, stream>>>(logits, pmax);
  k_redmax_f<<<1, 256, 0, stream>>>(pmax, red);
  k_redsum_p<<<1024, 256, 0, stream>>>(logits, red, psum);
  k_redsum_f<<<1, 256, 0, stream>>>(psum, red);
  k_agg<<<(NN + 3) / 4, 256, 0, stream>>>(msg, logits, rowptr, eid, red, out);
  k_node_mfma<<<(NN + 191) / 192, 256, 0, stream>>>(nf, out, U1p, ub1, U2p, ub2, out);
}

// Round 7
// 476.617 us; speedup vs baseline: 1.1221x; 1.1221x over previous
//
#include <hip/hip_runtime.h>
#include <hip/hip_bf16.h>
#include <stdint.h>

#define NN 100000
#define NE 600000
#define ND 128
#define ED 32
#define HID 128
#define SCANB 391  // ceil(NN/256)

using short8 = __attribute__((ext_vector_type(8))) short;
using f32x4  = __attribute__((ext_vector_type(4))) float;

// ---------- bf16 helpers (manual RNE, deterministic) ----------
__device__ __forceinline__ uint32_t f2bf(float f) {
  uint32_t u = __float_as_uint(f);
  return (u + 0x7FFFu + ((u >> 16) & 1u)) >> 16;
}
__device__ __forceinline__ short8 pack8(float4 a, float4 b) {
  short8 s;
  s[0] = (short)f2bf(a.x); s[1] = (short)f2bf(a.y);
  s[2] = (short)f2bf(a.z); s[3] = (short)f2bf(a.w);
  s[4] = (short)f2bf(b.x); s[5] = (short)f2bf(b.y);
  s[6] = (short)f2bf(b.z); s[7] = (short)f2bf(b.w);
  return s;
}

// ---------- weight pre-pack: frag-ordered bf16 ----------
// W?p[c*4096 + nt*512 + g*128 + c16*8 + j] = W[(c*32+g*8+j)*128 + nt*16+c16]
__global__ __launch_bounds__(256) void k_prep(
    const float* __restrict__ W1, const float* __restrict__ W2,
    const float* __restrict__ uW1, const float* __restrict__ uW2,
    short* __restrict__ W1p, short* __restrict__ W2p,
    short* __restrict__ U1p, short* __restrict__ U2p) {
  int o = blockIdx.x * 256 + threadIdx.x;
  const float* src; short* dst; int rel;
  if (o < 36864)      { rel = o;         src = W1;  dst = W1p; }
  else if (o < 53248) { rel = o - 36864; src = W2;  dst = W2p; }
  else if (o < 86016) { rel = o - 53248; src = uW1; dst = U1p; }
  else                { rel = o - 86016; src = uW2; dst = U2p; }
  int j = rel & 7, c16 = (rel >> 3) & 15, g = (rel >> 7) & 3, nt = (rel >> 9) & 7, c = rel >> 12;
  int k = c * 32 + g * 8 + j, n = nt * 16 + c16;
  dst[rel] = (short)f2bf(src[k * 128 + n]);
}

// ---------- node features fp32 -> bf16 ----------
__global__ __launch_bounds__(256) void k_prep_nf(const float* __restrict__ nf,
                                                 short* __restrict__ nfb) {
  const int total = NN * ND / 8;
  for (int u = blockIdx.x * 256 + threadIdx.x; u < total; u += gridDim.x * 256) {
    const float* s = nf + (size_t)u * 8;
    float4 v0 = *(const float4*)s, v1 = *(const float4*)(s + 4);
    *(short8*)(nfb + (size_t)u * 8) = pack8(v0, v1);
  }
}

// ---------- edge MLP: barrier-free direct-operand MFMA ----------
// A-frags gathered straight from nfb (16B/lane); B-frags read straight from
// packed weights (L1/L2-resident). LDS only for the layer-1->layer-2 transpose
// (sH), which is wave-private -> no __syncthreads after the sIdx stage.
__global__ __launch_bounds__(256, 3) void k_edge_mfma(
    const short* __restrict__ nfb, const float* __restrict__ ef,
    const short* __restrict__ W1p, const float* __restrict__ b1,
    const short* __restrict__ W2p, const float* __restrict__ b2,
    const float* __restrict__ aW, const int* __restrict__ ei,
    uint16_t* __restrict__ msg, float* __restrict__ logits) {
  __shared__ __align__(16) short sH[192 * 132];
  __shared__ int sIdx[384];

  const int tid = threadIdx.x;
  const int wv = tid >> 6, ln = tid & 63, cr = ln & 15, gp = ln >> 4;
  const int e0 = blockIdx.x * 192;   // grid is exactly NE/192, no tail
  const int wrow = wv * 48;

  if (tid < 192) {
    sIdx[tid] = ei[e0 + tid];
    sIdx[192 + tid] = ei[NE + e0 + tid];
  }
  __syncthreads();  // the only block barrier

  // this wave's source/dest node rows for its 3 m-tiles
  int rs0 = sIdx[wrow + cr], rs1 = sIdx[wrow + 16 + cr], rs2 = sIdx[wrow + 32 + cr];
  int rd0 = sIdx[192 + wrow + cr], rd1 = sIdx[192 + wrow + 16 + cr], rd2 = sIdx[192 + wrow + 32 + cr];

  f32x4 acc[3][8];
#pragma unroll
  for (int nt = 0; nt < 8; ++nt) {
    float bv = b1[nt * 16 + cr];
    acc[0][nt] = (f32x4){bv, bv, bv, bv};
    acc[1][nt] = acc[0][nt];
    acc[2][nt] = acc[0][nt];
  }

  short8 a_cur[3], a_nxt[3];
  a_cur[0] = *(const short8*)(nfb + (size_t)rs0 * ND + gp * 8);
  a_cur[1] = *(const short8*)(nfb + (size_t)rs1 * ND + gp * 8);
  a_cur[2] = *(const short8*)(nfb + (size_t)rs2 * ND + gp * 8);

  // ---- layer 1: 9 K-chunks (0-3 nf[row], 4-7 nf[col], 8 ef), no barriers ----
#pragma unroll
  for (int c = 0; c < 9; ++c) {
    // prefetch next chunk's A-frags (gathers overlap this chunk's MFMAs)
    if (c < 7) {
      const int base = ((c + 1) & 3) * 32 + gp * 8;
      if (c + 1 < 4) {
        a_nxt[0] = *(const short8*)(nfb + (size_t)rs0 * ND + base);
        a_nxt[1] = *(const short8*)(nfb + (size_t)rs1 * ND + base);
        a_nxt[2] = *(const short8*)(nfb + (size_t)rs2 * ND + base);
      } else {
        a_nxt[0] = *(const short8*)(nfb + (size_t)rd0 * ND + base);
        a_nxt[1] = *(const short8*)(nfb + (size_t)rd1 * ND + base);
        a_nxt[2] = *(const short8*)(nfb + (size_t)rd2 * ND + base);
      }
    } else if (c == 7) {
      const float* f0 = ef + (size_t)(e0 + wrow + cr) * ED + gp * 8;
      const float* f1 = ef + (size_t)(e0 + wrow + 16 + cr) * ED + gp * 8;
      const float* f2 = ef + (size_t)(e0 + wrow + 32 + cr) * ED + gp * 8;
      a_nxt[0] = pack8(*(const float4*)f0, *(const float4*)(f0 + 4));
      a_nxt[1] = pack8(*(const float4*)f1, *(const float4*)(f1 + 4));
      a_nxt[2] = pack8(*(const float4*)f2, *(const float4*)(f2 + 4));
    }
    // B in two 4-tile groups to bound VGPRs; MFMA between the groups
    const short* Wc = W1p + c * 4096;
#pragma unroll
    for (int h = 0; h < 2; ++h) {
      short8 bf0 = *(const short8*)(Wc + ((h * 4 + 0) * 4 + gp) * 128 + cr * 8);
      short8 bf1 = *(const short8*)(Wc + ((h * 4 + 1) * 4 + gp) * 128 + cr * 8);
      short8 bf2 = *(const short8*)(Wc + ((h * 4 + 2) * 4 + gp) * 128 + cr * 8);
      short8 bf3 = *(const short8*)(Wc + ((h * 4 + 3) * 4 + gp) * 128 + cr * 8);
#pragma unroll
      for (int mt = 0; mt < 3; ++mt) {
        acc[mt][h * 4 + 0] = __builtin_amdgcn_mfma_f32_16x16x32_bf16(a_cur[mt], bf0, acc[mt][h * 4 + 0], 0, 0, 0);
        acc[mt][h * 4 + 1] = __builtin_amdgcn_mfma_f32_16x16x32_bf16(a_cur[mt], bf1, acc[mt][h * 4 + 1], 0, 0, 0);
        acc[mt][h * 4 + 2] = __builtin_amdgcn_mfma_f32_16x16x32_bf16(a_cur[mt], bf2, acc[mt][h * 4 + 2], 0, 0, 0);
        acc[mt][h * 4 + 3] = __builtin_amdgcn_mfma_f32_16x16x32_bf16(a_cur[mt], bf3, acc[mt][h * 4 + 3], 0, 0, 0);
      }
    }
    a_cur[0] = a_nxt[0]; a_cur[1] = a_nxt[1]; a_cur[2] = a_nxt[2];
  }

  // relu -> sH (bf16). Rows wrow..wrow+47 are written and later read ONLY by
  // this wave -> in-wave lgkmcnt ordering suffices, no barrier.
#pragma unroll
  for (int mt = 0; mt < 3; ++mt)
#pragma unroll
    for (int nt = 0; nt < 8; ++nt)
#pragma unroll
      for (int rr = 0; rr < 4; ++rr)
        sH[(wrow + mt * 16 + gp * 4 + rr) * 132 + nt * 16 + cr] =
            (short)f2bf(fmaxf(acc[mt][nt][rr], 0.f));

  // ---- layer 2: K = 128, A from wave-private sH, B direct ----
  f32x4 acc2[3][8];
#pragma unroll
  for (int nt = 0; nt < 8; ++nt) {
    float bv = b2[nt * 16 + cr];
    acc2[0][nt] = (f32x4){bv, bv, bv, bv};
    acc2[1][nt] = acc2[0][nt];
    acc2[2][nt] = acc2[0][nt];
  }
#pragma unroll
  for (int c2 = 0; c2 < 4; ++c2) {
    short8 af0 = *(const short8*)&sH[(wrow + cr) * 132 + c2 * 32 + gp * 8];
    short8 af1 = *(const short8*)&sH[(wrow + 16 + cr) * 132 + c2 * 32 + gp * 8];
    short8 af2 = *(const short8*)&sH[(wrow + 32 + cr) * 132 + c2 * 32 + gp * 8];
    const short* Wc = W2p + c2 * 4096;
#pragma unroll
    for (int h = 0; h < 2; ++h) {
      short8 bf0 = *(const short8*)(Wc + ((h * 4 + 0) * 4 + gp) * 128 + cr * 8);
      short8 bf1 = *(const short8*)(Wc + ((h * 4 + 1) * 4 + gp) * 128 + cr * 8);
      short8 bf2 = *(const short8*)(Wc + ((h * 4 + 2) * 4 + gp) * 128 + cr * 8);
      short8 bf3 = *(const short8*)(Wc + ((h * 4 + 3) * 4 + gp) * 128 + cr * 8);
      acc2[0][h * 4 + 0] = __builtin_amdgcn_mfma_f32_16x16x32_bf16(af0, bf0, acc2[0][h * 4 + 0], 0, 0, 0);
      acc2[1][h * 4 + 0] = __builtin_amdgcn_mfma_f32_16x16x32_bf16(af1, bf0, acc2[1][h * 4 + 0], 0, 0, 0);
      acc2[2][h * 4 + 0] = __builtin_amdgcn_mfma_f32_16x16x32_bf16(af2, bf0, acc2[2][h * 4 + 0], 0, 0, 0);
      acc2[0][h * 4 + 1] = __builtin_amdgcn_mfma_f32_16x16x32_bf16(af0, bf1, acc2[0][h * 4 + 1], 0, 0, 0);
      acc2[1][h * 4 + 1] = __builtin_amdgcn_mfma_f32_16x16x32_bf16(af1, bf1, acc2[1][h * 4 + 1], 0, 0, 0);
      acc2[2][h * 4 + 1] = __builtin_amdgcn_mfma_f32_16x16x32_bf16(af2, bf1, acc2[2][h * 4 + 1], 0, 0, 0);
      acc2[0][h * 4 + 2] = __builtin_amdgcn_mfma_f32_16x16x32_bf16(af0, bf2, acc2[0][h * 4 + 2], 0, 0, 0);
      acc2[1][h * 4 + 2] = __builtin_amdgcn_mfma_f32_16x16x32_bf16(af1, bf2, acc2[1][h * 4 + 2], 0, 0, 0);
      acc2[2][h * 4 + 2] = __builtin_amdgcn_mfma_f32_16x16x32_bf16(af2, bf2, acc2[2][h * 4 + 2], 0, 0, 0);
      acc2[0][h * 4 + 3] = __builtin_amdgcn_mfma_f32_16x16x32_bf16(af0, bf3, acc2[0][h * 4 + 3], 0, 0, 0);
      acc2[1][h * 4 + 3] = __builtin_amdgcn_mfma_f32_16x16x32_bf16(af1, bf3, acc2[1][h * 4 + 3], 0, 0, 0);
      acc2[2][h * 4 + 3] = __builtin_amdgcn_mfma_f32_16x16x32_bf16(af2, bf3, acc2[2][h * 4 + 3], 0, 0, 0);
    }
  }

  // attention logits (register-only; reduce over the 16 col-lanes)
#pragma unroll
  for (int mt = 0; mt < 3; ++mt)
#pragma unroll
    for (int rr = 0; rr < 4; ++rr) {
      float p = 0.f;
#pragma unroll
      for (int nt = 0; nt < 8; ++nt) p += acc2[mt][nt][rr] * aW[nt * 16 + cr];
      p += __shfl_xor(p, 1, 64);
      p += __shfl_xor(p, 2, 64);
      p += __shfl_xor(p, 4, 64);
      p += __shfl_xor(p, 8, 64);
      if (cr == 0) logits[e0 + wrow + mt * 16 + gp * 4 + rr] = p;
    }

  // messages -> sH (bf16, wave-private rows) -> per-wave coalesced global write
#pragma unroll
  for (int mt = 0; mt < 3; ++mt)
#pragma unroll
    for (int nt = 0; nt < 8; ++nt)
#pragma unroll
      for (int rr = 0; rr < 4; ++rr)
        sH[(wrow + mt * 16 + gp * 4 + rr) * 132 + nt * 16 + cr] =
            (short)f2bf(acc2[mt][nt][rr]);
#pragma unroll
  for (int it = 0; it < 12; ++it) {
    int row = wrow + it * 4 + (ln >> 4), o8 = cr * 8;
    *(short8*)(msg + (size_t)(e0 + row) * HID + o8) = *(const short8*)&sH[row * 132 + o8];
  }
}

// ---------- node update MLP via MFMA (+ residual) — unchanged (proven) ----------
__global__ __launch_bounds__(256, 2) void k_node_mfma(
    const float* __restrict__ nf, const float* __restrict__ agg,
    const short* __restrict__ U1p, const float* __restrict__ b1,
    const short* __restrict__ U2p, const float* __restrict__ b2,
    float* __restrict__ out) {
  __shared__ __align__(16) short sA[192 * 40];
  __shared__ __align__(16) short sB[4096];
  __shared__ __align__(16) short sH[192 * 136];

  const int tid = threadIdx.x;
  const int wv = tid >> 6, ln = tid & 63, cr = ln & 15, gp = ln >> 4;
  const int n0 = blockIdx.x * 192;
  const int wrow = wv * 48;

  float bia[8], bia2[8];
#pragma unroll
  for (int nt = 0; nt < 8; ++nt) {
    bia[nt] = b1[nt * 16 + cr];
    bia2[nt] = b2[nt * 16 + cr];
  }
  f32x4 acc[3][8];
#pragma unroll
  for (int mt = 0; mt < 3; ++mt)
#pragma unroll
    for (int nt = 0; nt < 8; ++nt)
      acc[mt][nt] = (f32x4){bia[nt], bia[nt], bia[nt], bia[nt]};

  for (int c = 0; c < 8; ++c) {
#pragma unroll
    for (int it = 0; it < 3; ++it) {
      int row = it * 64 + (tid >> 2), k8 = (tid & 3) * 8;
      int n = n0 + row; if (n >= NN) n = NN - 1;
      const float* src = (c < 4) ? nf + (size_t)n * ND + c * 32 + k8
                                 : agg + (size_t)n * ND + (c - 4) * 32 + k8;
      float4 v0 = *(const float4*)src, v1 = *(const float4*)(src + 4);
      *(short8*)&sA[row * 40 + k8] = pack8(v0, v1);
    }
    {
      const short8* wsrc = (const short8*)(U1p + c * 4096);
      short8 t0 = wsrc[tid], t1 = wsrc[tid + 256];
      ((short8*)sB)[tid] = t0; ((short8*)sB)[tid + 256] = t1;
    }
    __syncthreads();
    short8 af[3];
#pragma unroll
    for (int mt = 0; mt < 3; ++mt)
      af[mt] = *(const short8*)&sA[(wrow + mt * 16 + cr) * 40 + gp * 8];
#pragma unroll
    for (int nt = 0; nt < 8; ++nt) {
      short8 bfr = *(const short8*)&sB[(nt * 4 + gp) * 128 + cr * 8];
#pragma unroll
      for (int mt = 0; mt < 3; ++mt)
        acc[mt][nt] = __builtin_amdgcn_mfma_f32_16x16x32_bf16(af[mt], bfr, acc[mt][nt], 0, 0, 0);
    }
    __syncthreads();
  }

#pragma unroll
  for (int mt = 0; mt < 3; ++mt)
#pragma unroll
    for (int nt = 0; nt < 8; ++nt)
#pragma unroll
      for (int rr = 0; rr < 4; ++rr)
        sH[(wrow + mt * 16 + gp * 4 + rr) * 136 + nt * 16 + cr] =
            (short)f2bf(fmaxf(acc[mt][nt][rr], 0.f));
  __syncthreads();

  f32x4 acc2[3][8];
#pragma unroll
  for (int mt = 0; mt < 3; ++mt)
#pragma unroll
    for (int nt = 0; nt < 8; ++nt)
      acc2[mt][nt] = (f32x4){bia2[nt], bia2[nt], bia2[nt], bia2[nt]};
  for (int c2 = 0; c2 < 4; ++c2) {
    {
      const short8* wsrc = (const short8*)(U2p + c2 * 4096);
      short8 t0 = wsrc[tid], t1 = wsrc[tid + 256];
      ((short8*)sB)[tid] = t0; ((short8*)sB)[tid + 256] = t1;
    }
    __syncthreads();
    short8 af[3];
#pragma unroll
    for (int mt = 0; mt < 3; ++mt)
      af[mt] = *(const short8*)&sH[(wrow + mt * 16 + cr) * 136 + c2 * 32 + gp * 8];
#pragma unroll
    for (int nt = 0; nt < 8; ++nt) {
      short8 bfr = *(const short8*)&sB[(nt * 4 + gp) * 128 + cr * 8];
#pragma unroll
      for (int mt = 0; mt < 3; ++mt)
        acc2[mt][nt] = __builtin_amdgcn_mfma_f32_16x16x32_bf16(af[mt], bfr, acc2[mt][nt], 0, 0, 0);
    }
    __syncthreads();
  }

#pragma unroll
  for (int mt = 0; mt < 3; ++mt)
#pragma unroll
    for (int rr = 0; rr < 4; ++rr) {
      int n = n0 + wrow + mt * 16 + gp * 4 + rr;
      if (n < NN) {
#pragma unroll
        for (int nt = 0; nt < 8; ++nt) {
          int col = nt * 16 + cr;
          out[(size_t)n * ND + col] = acc2[mt][nt][rr] + nf[(size_t)n * ND + col];
        }
      }
    }
}

// ---------- softmax reductions ----------
__device__ __forceinline__ float block_reduce_max(float m) {
#pragma unroll
  for (int s = 1; s < 64; s <<= 1) m = fmaxf(m, __shfl_xor(m, s, 64));
  __shared__ float sm[4];
  if ((threadIdx.x & 63) == 0) sm[threadIdx.x >> 6] = m;
  __syncthreads();
  return fmaxf(fmaxf(sm[0], sm[1]), fmaxf(sm[2], sm[3]));
}
__device__ __forceinline__ float block_reduce_sum(float v) {
#pragma unroll
  for (int s = 1; s < 64; s <<= 1) v += __shfl_xor(v, s, 64);
  __shared__ float sv[4];
  if ((threadIdx.x & 63) == 0) sv[threadIdx.x >> 6] = v;
  __syncthreads();
  return sv[0] + sv[1] + sv[2] + sv[3];
}

__global__ __launch_bounds__(256) void k_redmax_p(const float* __restrict__ logits,
                                                 float* __restrict__ pmax) {
  float m = -3.402823466e38f;
  for (int i = blockIdx.x * 256 + threadIdx.x; i < NE; i += 1024 * 256)
    m = fmaxf(m, logits[i]);
  m = block_reduce_max(m);
  if (threadIdx.x == 0) pmax[blockIdx.x] = m;
}
__global__ __launch_bounds__(256) void k_redmax_f(const float* __restrict__ p,
                                                 float* __restrict__ red) {
  float m = fmaxf(fmaxf(p[threadIdx.x], p[threadIdx.x + 256]),
                  fmaxf(p[threadIdx.x + 512], p[threadIdx.x + 768]));
  m = block_reduce_max(m);
  if (threadIdx.x == 0) red[0] = m;
}
__global__ __launch_bounds__(256) void k_redsum_p(const float* __restrict__ logits,
                                                 const float* __restrict__ red,
                                                 float* __restrict__ psum) {
  float gm = red[0], s = 0.f;
  for (int i = blockIdx.x * 256 + threadIdx.x; i < NE; i += 1024 * 256)
    s += expf(logits[i] - gm);
  s = block_reduce_sum(s);
  if (threadIdx.x == 0) psum[blockIdx.x] = s;
}
__global__ __launch_bounds__(256) void k_redsum_f(const float* __restrict__ p,
                                                 float* __restrict__ red) {
  float s = p[threadIdx.x] + p[threadIdx.x + 256] + p[threadIdx.x + 512] +
            p[threadIdx.x + 768];
  s = block_reduce_sum(s);
  if (threadIdx.x == 0) red[1] = 1.0f / s;
}

// ---------- CSR build ----------
__global__ __launch_bounds__(256) void k_zero_cnt(int* __restrict__ cnt) {
  int i = blockIdx.x * 256 + threadIdx.x;
  if (i < NN) cnt[i] = 0;
}
__global__ __launch_bounds__(256) void k_hist(const int* __restrict__ ei,
                                              int* __restrict__ cnt) {
  int e = blockIdx.x * 256 + threadIdx.x;
  if (e < NE) atomicAdd(&cnt[ei[NE + e]], 1);
}
__global__ __launch_bounds__(256) void k_scan_bsum(const int* __restrict__ cnt,
                                                   int* __restrict__ bsum) {
  int i = blockIdx.x * 256 + threadIdx.x;
  int v = (i < NN) ? cnt[i] : 0;
#pragma unroll
  for (int s = 1; s < 64; s <<= 1) v += __shfl_xor(v, s, 64);
  __shared__ int sv[4];
  if ((threadIdx.x & 63) == 0) sv[threadIdx.x >> 6] = v;
  __syncthreads();
  if (threadIdx.x == 0) bsum[blockIdx.x] = sv[0] + sv[1] + sv[2] + sv[3];
}
__global__ __launch_bounds__(512) void k_scan_boff(const int* __restrict__ bsum,
                                                   int* __restrict__ boff,
                                                   int* __restrict__ rowptr) {
  __shared__ int s[512];
  int t = threadIdx.x;
  int v = (t < SCANB) ? bsum[t] : 0;
  s[t] = v;
  __syncthreads();
  for (int off = 1; off < 512; off <<= 1) {
    int u = (t >= off) ? s[t - off] : 0;
    __syncthreads();
    s[t] += u;
    __syncthreads();
  }
  if (t < SCANB) boff[t] = s[t] - v;  // exclusive
  if (t == 0) rowptr[NN] = NE;
}
__global__ __launch_bounds__(256) void k_scan_final(int* __restrict__ cnt,
                                                    const int* __restrict__ boff,
                                                    int* __restrict__ rowptr) {
  __shared__ int s[256];
  int b = blockIdx.x, t = threadIdx.x, i = b * 256 + t;
  int v = (i < NN) ? cnt[i] : 0;
  s[t] = v;
  __syncthreads();
  for (int off = 1; off < 256; off <<= 1) {
    int u = (t >= off) ? s[t - off] : 0;
    __syncthreads();
    s[t] += u;
    __syncthreads();
  }
  int excl = s[t] - v + boff[b];
  if (i < NN) { rowptr[i] = excl; cnt[i] = excl; }  // cnt becomes the fill cursor
}
__global__ __launch_bounds__(256) void k_fill(const int* __restrict__ ei,
                                              int* __restrict__ cursor,
                                              int* __restrict__ eid) {
  int e = blockIdx.x * 256 + threadIdx.x;
  if (e >= NE) return;
  int c = ei[NE + e];
  int pos = atomicAdd(&cursor[c], 1);
  eid[pos] = e;
}

// ---------- CSR gather-aggregate (weights fused): one wave per node ----------
__global__ __launch_bounds__(256) void k_agg(
    const uint16_t* __restrict__ msg, const float* __restrict__ logits,
    const int* __restrict__ rowptr, const int* __restrict__ eid,
    const float* __restrict__ red, float* __restrict__ out) {
  int n = blockIdx.x * 4 + (threadIdx.x >> 6);
  int lane = threadIdx.x & 63;
  if (n >= NN) return;
  float gm = red[0], inv = red[1];
  int i0 = rowptr[n], i1 = rowptr[n + 1];
  float a0 = 0.f, a1 = 0.f;
  for (int i = i0; i < i1; ++i) {
    int e = eid[i];
    float wt = expf(logits[e] - gm) * inv;
    uint32_t pk = *(const uint32_t*)(msg + (size_t)e * HID + lane * 2);
    a0 += wt * __uint_as_float(pk << 16);
    a1 += wt * __uint_as_float(pk & 0xFFFF0000u);
  }
  *(float2*)(out + (size_t)n * ND + lane * 2) = make_float2(a0, a1);
}

extern "C" void kernel_launch(void* const* d_in, const int* in_sizes, int n_in,
                              void* d_out, int out_size, void* d_ws, size_t ws_size,
                              hipStream_t stream) {
  const float* nf  = (const float*)d_in[0];
  const float* ef  = (const float*)d_in[1];
  const float* mW1 = (const float*)d_in[2];
  const float* mb1 = (const float*)d_in[3];
  const float* mW2 = (const float*)d_in[4];
  const float* mb2 = (const float*)d_in[5];
  const float* aW  = (const float*)d_in[6];
  // d_in[7] = a_b — unused (softmax is shift-invariant)
  const float* uW1 = (const float*)d_in[8];
  const float* ub1 = (const float*)d_in[9];
  const float* uW2 = (const float*)d_in[10];
  const float* ub2 = (const float*)d_in[11];
  const int*   ei  = (const int*)d_in[12];
  float* out = (float*)d_out;

  // ws layout (bytes):
  //   0          msg bf16 [NE*128]            153,600,000
  //   153600000  logits f32 [NE]                2,400,000
  //   156000000  pmax[1024] psum[1024] red          8,256
  //   156008256  W1p/W2p/U1p/U2p packed bf16      204,800
  //   156213056  rowptr/cnt/eid/bsum/boff       3,204,100
  //   159420416  nfb bf16 [NN*128]             25,600,000   -> total ~185MB
  char* ws = (char*)d_ws;
  uint16_t* msg = (uint16_t*)ws;
  float* logits = (float*)(ws + 153600000);
  float* pmax = (float*)(ws + 156000000);
  float* psum = pmax + 1024;
  float* red  = psum + 1024;
  short* W1p = (short*)(ws + 156008256);
  short* W2p = W1p + 36864;
  short* U1p = W2p + 16384;
  short* U2p = U1p + 32768;
  int* rowptr = (int*)(ws + 156213056);
  int* cnt    = rowptr + (NN + 1);
  int* eid    = cnt + NN;
  int* bsum   = eid + NE;
  int* boff   = bsum + 512;
  short* nfb  = (short*)(ws + 159420416);

  k_prep<<<400, 256, 0, stream>>>(mW1, mW2, uW1, uW2, W1p, W2p, U1p, U2p);
  k_prep_nf<<<2048, 256, 0, stream>>>(nf, nfb);
  k_zero_cnt<<<SCANB, 256, 0, stream>>>(cnt);
  k_hist<<<(NE + 255) / 256, 256, 0, stream>>>(ei, cnt);
  k_scan_bsum<<<SCANB, 256, 0, stream>>>(cnt, bsum);
  k_scan_boff<<<1, 512, 0, stream>>>(bsum, boff, rowptr);
  k_scan_final<<<SCANB, 256, 0, stream>>>(cnt, boff, rowptr);
  k_fill<<<(NE + 255) / 256, 256, 0, stream>>>(ei, cnt, eid);
  k_edge_mfma<<<NE / 192, 256, 0, stream>>>(nfb, ef, W1p, mb1, W2p, mb2, aW, ei, msg, logits);
  k_redmax_p<<<1024, 256, 0, stream>>>(logits, pmax);
  k_redmax_f<<<1, 256, 0, stream>>>(pmax, red);
  k_redsum_p<<<1024, 256, 0, stream>>>(logits, red, psum);
  k_redsum_f<<<1, 256, 0, stream>>>(psum, red);
  k_agg<<<(NN + 3) / 4, 256, 0, stream>>>(msg, logits, rowptr, eid, red, out);
  k_node_mfma<<<(NN + 191) / 192, 256, 0, stream>>>(nf, out, U1p, ub1, U2p, ub2, out);
}

// Round 8
// 382.858 us; speedup vs baseline: 1.3969x; 1.2449x over previous
//
#include <hip/hip_runtime.h>
#include <hip/hip_bf16.h>
#include <stdint.h>

#define NN 100000
#define NE 600000
#define ND 128
#define ED 32
#define HID 128
#define SCANB 391  // ceil(NN/256)

using short8 = __attribute__((ext_vector_type(8))) short;
using f32x4  = __attribute__((ext_vector_type(4))) float;

// ---------- bf16 helpers (manual RNE, deterministic) ----------
__device__ __forceinline__ uint32_t f2bf(float f) {
  uint32_t u = __float_as_uint(f);
  return (u + 0x7FFFu + ((u >> 16) & 1u)) >> 16;
}
__device__ __forceinline__ short8 pack8(float4 a, float4 b) {
  short8 s;
  s[0] = (short)f2bf(a.x); s[1] = (short)f2bf(a.y);
  s[2] = (short)f2bf(a.z); s[3] = (short)f2bf(a.w);
  s[4] = (short)f2bf(b.x); s[5] = (short)f2bf(b.y);
  s[6] = (short)f2bf(b.z); s[7] = (short)f2bf(b.w);
  return s;
}

// ---------- weight pre-pack: frag-ordered bf16 ----------
__global__ __launch_bounds__(256) void k_prep(
    const float* __restrict__ W1, const float* __restrict__ W2,
    const float* __restrict__ uW1, const float* __restrict__ uW2,
    short* __restrict__ W1p, short* __restrict__ W2p,
    short* __restrict__ U1p, short* __restrict__ U2p) {
  int o = blockIdx.x * 256 + threadIdx.x;
  const float* src; short* dst; int rel;
  if (o < 36864)      { rel = o;         src = W1;  dst = W1p; }
  else if (o < 53248) { rel = o - 36864; src = W2;  dst = W2p; }
  else if (o < 86016) { rel = o - 53248; src = uW1; dst = U1p; }
  else                { rel = o - 86016; src = uW2; dst = U2p; }
  int j = rel & 7, c16 = (rel >> 3) & 15, g = (rel >> 7) & 3, nt = (rel >> 9) & 7, c = rel >> 12;
  int k = c * 32 + g * 8 + j, n = nt * 16 + c16;
  dst[rel] = (short)f2bf(src[k * 128 + n]);
}

// ---------- node features fp32 -> bf16 (halves gather bytes) ----------
__global__ __launch_bounds__(256) void k_prep_nf(const float* __restrict__ nf,
                                                 short* __restrict__ nfb) {
  const int total = NN * ND / 8;
  for (int u = blockIdx.x * 256 + threadIdx.x; u < total; u += gridDim.x * 256) {
    const float* s = nf + (size_t)u * 8;
    float4 v0 = *(const float4*)s, v1 = *(const float4*)(s + 4);
    *(short8*)(nfb + (size_t)u * 8) = pack8(v0, v1);
  }
}

// ---------- edge MLP via MFMA (R5 structure + bf16 staging gathers) ----------
__global__ __launch_bounds__(256, 2) void k_edge_mfma(
    const short* __restrict__ nfb, const float* __restrict__ ef,
    const short* __restrict__ W1p, const float* __restrict__ b1,
    const short* __restrict__ W2p, const float* __restrict__ b2,
    const float* __restrict__ aW, const int* __restrict__ ei,
    uint16_t* __restrict__ msg, float* __restrict__ logits) {
  __shared__ __align__(16) short sA[192 * 40];
  __shared__ __align__(16) short sB[4096];
  __shared__ __align__(16) short sH[192 * 136];
  __shared__ int sIdx[384];

  const int tid = threadIdx.x;
  const int wv = tid >> 6, ln = tid & 63, cr = ln & 15, gp = ln >> 4;
  const int e0 = blockIdx.x * 192;   // grid exactly NE/192
  const int wrow = wv * 48;

  if (tid < 192) {
    sIdx[tid] = ei[e0 + tid];
    sIdx[192 + tid] = ei[NE + e0 + tid];
  }

  float bia[8], aWr[8], bia2[8];
#pragma unroll
  for (int nt = 0; nt < 8; ++nt) {
    bia[nt] = b1[nt * 16 + cr];
    bia2[nt] = b2[nt * 16 + cr];
    aWr[nt] = aW[nt * 16 + cr];
  }
  f32x4 acc[3][8];
#pragma unroll
  for (int mt = 0; mt < 3; ++mt)
#pragma unroll
    for (int nt = 0; nt < 8; ++nt)
      acc[mt][nt] = (f32x4){bia[nt], bia[nt], bia[nt], bia[nt]};
  __syncthreads();

  // layer 1: K = 288 (chunks 0-3: nfb[row], 4-7: nfb[col], 8: ef)
  for (int c = 0; c < 9; ++c) {
#pragma unroll
    for (int it = 0; it < 3; ++it) {
      int row = it * 64 + (tid >> 2), k8 = (tid & 3) * 8;
      if (c < 8) {
        const short* src = nfb + (size_t)sIdx[(c < 4 ? 0 : 192) + row] * ND +
                           (c & 3) * 32 + k8;
        *(short8*)&sA[row * 40 + k8] = *(const short8*)src;
      } else {
        const float* src = ef + (size_t)(e0 + row) * ED + k8;
        float4 v0 = *(const float4*)src, v1 = *(const float4*)(src + 4);
        *(short8*)&sA[row * 40 + k8] = pack8(v0, v1);
      }
    }
    {
      const short8* wsrc = (const short8*)(W1p + c * 4096);
      short8 t0 = wsrc[tid], t1 = wsrc[tid + 256];
      ((short8*)sB)[tid] = t0; ((short8*)sB)[tid + 256] = t1;
    }
    __syncthreads();
    short8 af[3];
#pragma unroll
    for (int mt = 0; mt < 3; ++mt)
      af[mt] = *(const short8*)&sA[(wrow + mt * 16 + cr) * 40 + gp * 8];
#pragma unroll
    for (int nt = 0; nt < 8; ++nt) {
      short8 bfr = *(const short8*)&sB[(nt * 4 + gp) * 128 + cr * 8];
#pragma unroll
      for (int mt = 0; mt < 3; ++mt)
        acc[mt][nt] = __builtin_amdgcn_mfma_f32_16x16x32_bf16(af[mt], bfr, acc[mt][nt], 0, 0, 0);
    }
    __syncthreads();
  }

  // relu -> sH (bf16)
#pragma unroll
  for (int mt = 0; mt < 3; ++mt)
#pragma unroll
    for (int nt = 0; nt < 8; ++nt)
#pragma unroll
      for (int rr = 0; rr < 4; ++rr)
        sH[(wrow + mt * 16 + gp * 4 + rr) * 136 + nt * 16 + cr] =
            (short)f2bf(fmaxf(acc[mt][nt][rr], 0.f));
  __syncthreads();

  // layer 2: K = 128
  f32x4 acc2[3][8];
#pragma unroll
  for (int mt = 0; mt < 3; ++mt)
#pragma unroll
    for (int nt = 0; nt < 8; ++nt)
      acc2[mt][nt] = (f32x4){bia2[nt], bia2[nt], bia2[nt], bia2[nt]};
  for (int c2 = 0; c2 < 4; ++c2) {
    {
      const short8* wsrc = (const short8*)(W2p + c2 * 4096);
      short8 t0 = wsrc[tid], t1 = wsrc[tid + 256];
      ((short8*)sB)[tid] = t0; ((short8*)sB)[tid + 256] = t1;
    }
    __syncthreads();
    short8 af[3];
#pragma unroll
    for (int mt = 0; mt < 3; ++mt)
      af[mt] = *(const short8*)&sH[(wrow + mt * 16 + cr) * 136 + c2 * 32 + gp * 8];
#pragma unroll
    for (int nt = 0; nt < 8; ++nt) {
      short8 bfr = *(const short8*)&sB[(nt * 4 + gp) * 128 + cr * 8];
#pragma unroll
      for (int mt = 0; mt < 3; ++mt)
        acc2[mt][nt] = __builtin_amdgcn_mfma_f32_16x16x32_bf16(af[mt], bfr, acc2[mt][nt], 0, 0, 0);
    }
    __syncthreads();
  }

  // attention logits (reduce over the 16 col-lanes)
#pragma unroll
  for (int mt = 0; mt < 3; ++mt)
#pragma unroll
    for (int rr = 0; rr < 4; ++rr) {
      float p = 0.f;
#pragma unroll
      for (int nt = 0; nt < 8; ++nt) p += acc2[mt][nt][rr] * aWr[nt];
      p += __shfl_xor(p, 1, 64);
      p += __shfl_xor(p, 2, 64);
      p += __shfl_xor(p, 4, 64);
      p += __shfl_xor(p, 8, 64);
      if (cr == 0) logits[e0 + wrow + mt * 16 + gp * 4 + rr] = p;
    }

  // messages -> sH (bf16) -> coalesced global write
#pragma unroll
  for (int mt = 0; mt < 3; ++mt)
#pragma unroll
    for (int nt = 0; nt < 8; ++nt)
#pragma unroll
      for (int rr = 0; rr < 4; ++rr)
        sH[(wrow + mt * 16 + gp * 4 + rr) * 136 + nt * 16 + cr] =
            (short)f2bf(acc2[mt][nt][rr]);
  __syncthreads();
#pragma unroll
  for (int it = 0; it < 12; ++it) {
    int row = it * 16 + (tid >> 4), o8 = (tid & 15) * 8;
    *(short8*)(msg + (size_t)(e0 + row) * HID + o8) = *(const short8*)&sH[row * 136 + o8];
  }
}

// ---------- node update MLP via MFMA (+ residual) ----------
__global__ __launch_bounds__(256, 2) void k_node_mfma(
    const float* __restrict__ nf, const float* __restrict__ agg,
    const short* __restrict__ U1p, const float* __restrict__ b1,
    const short* __restrict__ U2p, const float* __restrict__ b2,
    float* __restrict__ out) {
  __shared__ __align__(16) short sA[192 * 40];
  __shared__ __align__(16) short sB[4096];
  __shared__ __align__(16) short sH[192 * 136];

  const int tid = threadIdx.x;
  const int wv = tid >> 6, ln = tid & 63, cr = ln & 15, gp = ln >> 4;
  const int n0 = blockIdx.x * 192;
  const int wrow = wv * 48;

  float bia[8], bia2[8];
#pragma unroll
  for (int nt = 0; nt < 8; ++nt) {
    bia[nt] = b1[nt * 16 + cr];
    bia2[nt] = b2[nt * 16 + cr];
  }
  f32x4 acc[3][8];
#pragma unroll
  for (int mt = 0; mt < 3; ++mt)
#pragma unroll
    for (int nt = 0; nt < 8; ++nt)
      acc[mt][nt] = (f32x4){bia[nt], bia[nt], bia[nt], bia[nt]};

  for (int c = 0; c < 8; ++c) {
#pragma unroll
    for (int it = 0; it < 3; ++it) {
      int row = it * 64 + (tid >> 2), k8 = (tid & 3) * 8;
      int n = n0 + row; if (n >= NN) n = NN - 1;
      const float* src = (c < 4) ? nf + (size_t)n * ND + c * 32 + k8
                                 : agg + (size_t)n * ND + (c - 4) * 32 + k8;
      float4 v0 = *(const float4*)src, v1 = *(const float4*)(src + 4);
      *(short8*)&sA[row * 40 + k8] = pack8(v0, v1);
    }
    {
      const short8* wsrc = (const short8*)(U1p + c * 4096);
      short8 t0 = wsrc[tid], t1 = wsrc[tid + 256];
      ((short8*)sB)[tid] = t0; ((short8*)sB)[tid + 256] = t1;
    }
    __syncthreads();
    short8 af[3];
#pragma unroll
    for (int mt = 0; mt < 3; ++mt)
      af[mt] = *(const short8*)&sA[(wrow + mt * 16 + cr) * 40 + gp * 8];
#pragma unroll
    for (int nt = 0; nt < 8; ++nt) {
      short8 bfr = *(const short8*)&sB[(nt * 4 + gp) * 128 + cr * 8];
#pragma unroll
      for (int mt = 0; mt < 3; ++mt)
        acc[mt][nt] = __builtin_amdgcn_mfma_f32_16x16x32_bf16(af[mt], bfr, acc[mt][nt], 0, 0, 0);
    }
    __syncthreads();
  }

#pragma unroll
  for (int mt = 0; mt < 3; ++mt)
#pragma unroll
    for (int nt = 0; nt < 8; ++nt)
#pragma unroll
      for (int rr = 0; rr < 4; ++rr)
        sH[(wrow + mt * 16 + gp * 4 + rr) * 136 + nt * 16 + cr] =
            (short)f2bf(fmaxf(acc[mt][nt][rr], 0.f));
  __syncthreads();

  f32x4 acc2[3][8];
#pragma unroll
  for (int mt = 0; mt < 3; ++mt)
#pragma unroll
    for (int nt = 0; nt < 8; ++nt)
      acc2[mt][nt] = (f32x4){bia2[nt], bia2[nt], bia2[nt], bia2[nt]};
  for (int c2 = 0; c2 < 4; ++c2) {
    {
      const short8* wsrc = (const short8*)(U2p + c2 * 4096);
      short8 t0 = wsrc[tid], t1 = wsrc[tid + 256];
      ((short8*)sB)[tid] = t0; ((short8*)sB)[tid + 256] = t1;
    }
    __syncthreads();
    short8 af[3];
#pragma unroll
    for (int mt = 0; mt < 3; ++mt)
      af[mt] = *(const short8*)&sH[(wrow + mt * 16 + cr) * 136 + c2 * 32 + gp * 8];
#pragma unroll
    for (int nt = 0; nt < 8; ++nt) {
      short8 bfr = *(const short8*)&sB[(nt * 4 + gp) * 128 + cr * 8];
#pragma unroll
      for (int mt = 0; mt < 3; ++mt)
        acc2[mt][nt] = __builtin_amdgcn_mfma_f32_16x16x32_bf16(af[mt], bfr, acc2[mt][nt], 0, 0, 0);
    }
    __syncthreads();
  }

#pragma unroll
  for (int mt = 0; mt < 3; ++mt)
#pragma unroll
    for (int rr = 0; rr < 4; ++rr) {
      int n = n0 + wrow + mt * 16 + gp * 4 + rr;
      if (n < NN) {
#pragma unroll
        for (int nt = 0; nt < 8; ++nt) {
          int col = nt * 16 + cr;
          out[(size_t)n * ND + col] = acc2[mt][nt][rr] + nf[(size_t)n * ND + col];
        }
      }
    }
}

// ---------- softmax reductions ----------
__device__ __forceinline__ float block_reduce_max(float m) {
#pragma unroll
  for (int s = 1; s < 64; s <<= 1) m = fmaxf(m, __shfl_xor(m, s, 64));
  __shared__ float sm[4];
  if ((threadIdx.x & 63) == 0) sm[threadIdx.x >> 6] = m;
  __syncthreads();
  return fmaxf(fmaxf(sm[0], sm[1]), fmaxf(sm[2], sm[3]));
}
__device__ __forceinline__ float block_reduce_sum(float v) {
#pragma unroll
  for (int s = 1; s < 64; s <<= 1) v += __shfl_xor(v, s, 64);
  __shared__ float sv[4];
  if ((threadIdx.x & 63) == 0) sv[threadIdx.x >> 6] = v;
  __syncthreads();
  return sv[0] + sv[1] + sv[2] + sv[3];
}

__global__ __launch_bounds__(256) void k_redmax_p(const float* __restrict__ logits,
                                                 float* __restrict__ pmax) {
  float m = -3.402823466e38f;
  for (int i = blockIdx.x * 256 + threadIdx.x; i < NE; i += 1024 * 256)
    m = fmaxf(m, logits[i]);
  m = block_reduce_max(m);
  if (threadIdx.x == 0) pmax[blockIdx.x] = m;
}
__global__ __launch_bounds__(256) void k_redmax_f(const float* __restrict__ p,
                                                 float* __restrict__ red) {
  float m = fmaxf(fmaxf(p[threadIdx.x], p[threadIdx.x + 256]),
                  fmaxf(p[threadIdx.x + 512], p[threadIdx.x + 768]));
  m = block_reduce_max(m);
  if (threadIdx.x == 0) red[0] = m;
}
__global__ __launch_bounds__(256) void k_redsum_p(const float* __restrict__ logits,
                                                 const float* __restrict__ red,
                                                 float* __restrict__ psum) {
  float gm = red[0], s = 0.f;
  for (int i = blockIdx.x * 256 + threadIdx.x; i < NE; i += 1024 * 256)
    s += expf(logits[i] - gm);
  s = block_reduce_sum(s);
  if (threadIdx.x == 0) psum[blockIdx.x] = s;
}
__global__ __launch_bounds__(256) void k_redsum_f(const float* __restrict__ p,
                                                 float* __restrict__ red) {
  float s = p[threadIdx.x] + p[threadIdx.x + 256] + p[threadIdx.x + 512] +
            p[threadIdx.x + 768];
  s = block_reduce_sum(s);
  if (threadIdx.x == 0) red[1] = 1.0f / s;
}

// ---------- CSR build ----------
__global__ __launch_bounds__(256) void k_zero_cnt(int* __restrict__ cnt) {
  int i = blockIdx.x * 256 + threadIdx.x;
  if (i < NN) cnt[i] = 0;
}
__global__ __launch_bounds__(256) void k_hist(const int* __restrict__ ei,
                                              int* __restrict__ cnt) {
  int e = blockIdx.x * 256 + threadIdx.x;
  if (e < NE) atomicAdd(&cnt[ei[NE + e]], 1);
}
__global__ __launch_bounds__(256) void k_scan_bsum(const int* __restrict__ cnt,
                                                   int* __restrict__ bsum) {
  int i = blockIdx.x * 256 + threadIdx.x;
  int v = (i < NN) ? cnt[i] : 0;
#pragma unroll
  for (int s = 1; s < 64; s <<= 1) v += __shfl_xor(v, s, 64);
  __shared__ int sv[4];
  if ((threadIdx.x & 63) == 0) sv[threadIdx.x >> 6] = v;
  __syncthreads();
  if (threadIdx.x == 0) bsum[blockIdx.x] = sv[0] + sv[1] + sv[2] + sv[3];
}
__global__ __launch_bounds__(512) void k_scan_boff(const int* __restrict__ bsum,
                                                   int* __restrict__ boff,
                                                   int* __restrict__ rowptr) {
  __shared__ int s[512];
  int t = threadIdx.x;
  int v = (t < SCANB) ? bsum[t] : 0;
  s[t] = v;
  __syncthreads();
  for (int off = 1; off < 512; off <<= 1) {
    int u = (t >= off) ? s[t - off] : 0;
    __syncthreads();
    s[t] += u;
    __syncthreads();
  }
  if (t < SCANB) boff[t] = s[t] - v;  // exclusive
  if (t == 0) rowptr[NN] = NE;
}
__global__ __launch_bounds__(256) void k_scan_final(int* __restrict__ cnt,
                                                    const int* __restrict__ boff,
                                                    int* __restrict__ rowptr) {
  __shared__ int s[256];
  int b = blockIdx.x, t = threadIdx.x, i = b * 256 + t;
  int v = (i < NN) ? cnt[i] : 0;
  s[t] = v;
  __syncthreads();
  for (int off = 1; off < 256; off <<= 1) {
    int u = (t >= off) ? s[t - off] : 0;
    __syncthreads();
    s[t] += u;
    __syncthreads();
  }
  int excl = s[t] - v + boff[b];
  if (i < NN) { rowptr[i] = excl; cnt[i] = excl; }  // cnt becomes the fill cursor
}
__global__ __launch_bounds__(256) void k_fill(const int* __restrict__ ei,
                                              int* __restrict__ cursor,
                                              int* __restrict__ eid) {
  int e = blockIdx.x * 256 + threadIdx.x;
  if (e >= NE) return;
  int c = ei[NE + e];
  int pos = atomicAdd(&cursor[c], 1);
  eid[pos] = e;
}

// ---------- CSR gather-aggregate (weights fused): one wave per node ----------
__global__ __launch_bounds__(256) void k_agg(
    const uint16_t* __restrict__ msg, const float* __restrict__ logits,
    const int* __restrict__ rowptr, const int* __restrict__ eid,
    const float* __restrict__ red, float* __restrict__ out) {
  int n = blockIdx.x * 4 + (threadIdx.x >> 6);
  int lane = threadIdx.x & 63;
  if (n >= NN) return;
  float gm = red[0], inv = red[1];
  int i0 = rowptr[n], i1 = rowptr[n + 1];
  float a0 = 0.f, a1 = 0.f;
  for (int i = i0; i < i1; ++i) {
    int e = eid[i];
    float wt = expf(logits[e] - gm) * inv;
    uint32_t pk = *(const uint32_t*)(msg + (size_t)e * HID + lane * 2);
    a0 += wt * __uint_as_float(pk << 16);
    a1 += wt * __uint_as_float(pk & 0xFFFF0000u);
  }
  *(float2*)(out + (size_t)n * ND + lane * 2) = make_float2(a0, a1);
}

extern "C" void kernel_launch(void* const* d_in, const int* in_sizes, int n_in,
                              void* d_out, int out_size, void* d_ws, size_t ws_size,
                              hipStream_t stream) {
  const float* nf  = (const float*)d_in[0];
  const float* ef  = (const float*)d_in[1];
  const float* mW1 = (const float*)d_in[2];
  const float* mb1 = (const float*)d_in[3];
  const float* mW2 = (const float*)d_in[4];
  const float* mb2 = (const float*)d_in[5];
  const float* aW  = (const float*)d_in[6];
  // d_in[7] = a_b — unused (softmax is shift-invariant)
  const float* uW1 = (const float*)d_in[8];
  const float* ub1 = (const float*)d_in[9];
  const float* uW2 = (const float*)d_in[10];
  const float* ub2 = (const float*)d_in[11];
  const int*   ei  = (const int*)d_in[12];
  float* out = (float*)d_out;

  // ws layout (bytes):
  //   0          msg bf16 [NE*128]            153,600,000
  //   153600000  logits f32 [NE]                2,400,000
  //   156000000  pmax[1024] psum[1024] red          8,256
  //   156008256  W1p/W2p/U1p/U2p packed bf16      204,800
  //   156213056  rowptr/cnt/eid/bsum/boff       3,204,100
  //   159420416  nfb bf16 [NN*128]             25,600,000   -> total ~185MB
  char* ws = (char*)d_ws;
  uint16_t* msg = (uint16_t*)ws;
  float* logits = (float*)(ws + 153600000);
  float* pmax = (float*)(ws + 156000000);
  float* psum = pmax + 1024;
  float* red  = psum + 1024;
  short* W1p = (short*)(ws + 156008256);
  short* W2p = W1p + 36864;
  short* U1p = W2p + 16384;
  short* U2p = U1p + 32768;
  int* rowptr = (int*)(ws + 156213056);
  int* cnt    = rowptr + (NN + 1);
  int* eid    = cnt + NN;
  int* bsum   = eid + NE;
  int* boff   = bsum + 512;
  short* nfb  = (short*)(ws + 159420416);

  k_prep<<<400, 256, 0, stream>>>(mW1, mW2, uW1, uW2, W1p, W2p, U1p, U2p);
  k_prep_nf<<<2048, 256, 0, stream>>>(nf, nfb);
  k_zero_cnt<<<SCANB, 256, 0, stream>>>(cnt);
  k_hist<<<(NE + 255) / 256, 256, 0, stream>>>(ei, cnt);
  k_scan_bsum<<<SCANB, 256, 0, stream>>>(cnt, bsum);
  k_scan_boff<<<1, 512, 0, stream>>>(bsum, boff, rowptr);
  k_scan_final<<<SCANB, 256, 0, stream>>>(cnt, boff, rowptr);
  k_fill<<<(NE + 255) / 256, 256, 0, stream>>>(ei, cnt, eid);
  k_edge_mfma<<<NE / 192, 256, 0, stream>>>(nfb, ef, W1p, mb1, W2p, mb2, aW, ei, msg, logits);
  k_redmax_p<<<1024, 256, 0, stream>>>(logits, pmax);
  k_redmax_f<<<1, 256, 0, stream>>>(pmax, red);
  k_redsum_p<<<1024, 256, 0, stream>>>(logits, red, psum);
  k_redsum_f<<<1, 256, 0, stream>>>(psum, red);
  k_agg<<<(NN + 3) / 4, 256, 0, stream>>>(msg, logits, rowptr, eid, red, out);
  k_node_mfma<<<(NN + 191) / 192, 256, 0, stream>>>(nf, out, U1p, ub1, U2p, ub2, out);
}